// Round 5
// baseline (61.696 us; speedup 1.0000x reference)
//
#include <hip/hip_runtime.h>

#define R      8
#define K      17               // 2*r+1
#define W      512
#define H      512
#define ROWS   16               // output rows per block
#define INR    32               // input rows staged (ROWS + 2R)
#define VROWW  528              // v-region row: 8 halo + 512 + 8 halo floats
#define VOFF_F 7936             // v-region float offset: 65536B - 16*528*4B = 31744B

// Fused box filter, DMA-staged:
//   global --(global_load_lds x16B)--> LDS raw[32][512]  (64KB exactly)
//   vertical sliding sum (regs) -> halo-padded v-region (overlaps dead raw rows)
//   horizontal sliding sum (float4) -> global
// 512 threads (8 waves); LDS 64KB -> 2 blocks/CU.
__device__ __forceinline__ void gload_lds16(const float* g, float* l) {
    __builtin_amdgcn_global_load_lds(
        (const __attribute__((address_space(1))) void*)g,
        (__attribute__((address_space(3))) void*)l, 16, 0, 0);
}

__global__ __launch_bounds__(512, 4)
void box_dma(const float* __restrict__ x, float* __restrict__ out) {
    const int plane = blockIdx.y;              // n*C + c (128 planes)
    const int gy0   = blockIdx.x * ROWS;       // strip start row
    const float* __restrict__ src = x   + (size_t)plane * (W * H);
    float* __restrict__       dst = out + (size_t)plane * (W * H);

    __shared__ __align__(16) float s[INR * W]; // 65,536 B exactly

    const int tid  = threadIdx.x;
    const int wave = tid >> 6;
    const int lane = tid & 63;
    const float inv_k = 1.0f / (float)K;

    // ---- Phase 1: DMA-stage 32 rows x 512 cols. 64 chunks of 1KB; 8/wave.
    // Chunk c: row r=c>>1, half hf=c&1. LDS dest = c*1024 (wave-uniform base,
    // HW adds lane*16). Global src per-lane. OOB rows -> vector-zero instead.
    #pragma unroll
    for (int i = 0; i < 8; ++i) {
        const int c  = wave * 8 + i;
        const int r  = c >> 1;
        const int hf = c & 1;
        const int gy = gy0 - R + r;
        char* ldsbase = (char*)s + c * 1024;
        if ((unsigned)gy < (unsigned)H) {
            const float* gp = src + gy * W + hf * 256 + lane * 4;
            gload_lds16(gp, (float*)ldsbase);
        } else {
            *reinterpret_cast<float4*>(ldsbase + lane * 16) =
                make_float4(0.f, 0.f, 0.f, 0.f);
        }
    }
    __syncthreads();   // drains vmcnt before barrier

    // ---- Phase 2a: read own column's 32 raw values into regs ----
    const int col = tid;                       // 0..511
    float r32[INR];
    #pragma unroll
    for (int j = 0; j < INR; ++j) r32[j] = s[j * W + col];
    __syncthreads();   // all raw reads complete before v-region overwrites

    // ---- Phase 2b: vertical sliding sums -> halo-padded v rows ----
    {
        float sum = 0.0f;
        #pragma unroll
        for (int j = 0; j < K; ++j) sum += r32[j];
        s[VOFF_F + 0 * VROWW + 8 + col] = sum * inv_k;
        #pragma unroll
        for (int i = 1; i < ROWS; ++i) {
            sum += r32[i + 2 * R] - r32[i - 1];
            s[VOFF_F + i * VROWW + 8 + col] = sum * inv_k;
        }
    }
    // zero the 8-col halos: 16 rows x 4 float4 slots (left 0,4; right 520,524)
    if (tid < 64) {
        const int row = tid >> 2;
        const int q   = tid & 3;
        const int c4  = (q == 0) ? 0 : (q == 1) ? 4 : (q == 2) ? 520 : 524;
        *reinterpret_cast<float4*>(&s[VOFF_F + row * VROWW + c4]) =
            make_float4(0.f, 0.f, 0.f, 0.f);
    }
    __syncthreads();

    // ---- Phase 3: horizontal box sum, float4 LDS reads -> float4 stores ----
    // 2048 quads (16 rows x 128) over 512 threads = 4 each
    #pragma unroll
    for (int it = 0; it < 4; ++it) {
        const int q  = tid + it * 512;
        const int y  = q >> 7;                 // 0..15
        const int x4 = (q & 127) * 4;          // 0..508
        const float* vrow = s + VOFF_F + y * VROWW + 8;   // col 0

        const float4 f0 = *reinterpret_cast<const float4*>(vrow + x4 - 8);
        const float4 f1 = *reinterpret_cast<const float4*>(vrow + x4 - 4);
        const float4 f2 = *reinterpret_cast<const float4*>(vrow + x4);
        const float4 f3 = *reinterpret_cast<const float4*>(vrow + x4 + 4);
        const float4 f4 = *reinterpret_cast<const float4*>(vrow + x4 + 8);

        float o0 = f0.x + f0.y + f0.z + f0.w
                 + f1.x + f1.y + f1.z + f1.w
                 + f2.x + f2.y + f2.z + f2.w
                 + f3.x + f3.y + f3.z + f3.w
                 + f4.x;                       // 17 taps: cols x4-8 .. x4+8
        const float o1 = o0 - f0.x + f4.y;
        const float o2 = o1 - f0.y + f4.z;
        const float o3 = o2 - f0.z + f4.w;

        float4 o;
        o.x = o0 * inv_k; o.y = o1 * inv_k; o.z = o2 * inv_k; o.w = o3 * inv_k;
        *reinterpret_cast<float4*>(&dst[(gy0 + y) * W + x4]) = o;
    }
}

extern "C" void kernel_launch(void* const* d_in, const int* in_sizes, int n_in,
                              void* d_out, int out_size, void* d_ws, size_t ws_size,
                              hipStream_t stream) {
    const float* x = (const float*)d_in[0];
    float* out = (float*)d_out;
    // x: (8, 16, 512, 512) fp32; r = 8 fixed
    dim3 grid(H / ROWS, 8 * 16);   // (32 strips, 128 planes)
    box_dma<<<grid, dim3(512), 0, stream>>>(x, out);
}

// Round 7
// 61.652 us; speedup vs baseline: 1.0007x; 1.0007x over previous
//
#include <hip/hip_runtime.h>

#define R      8
#define K      17               // 2*r+1
#define W      512
#define H      512
#define ROWS   16               // output rows per block
#define INR    32               // input rows staged (ROWS + 2R)
#define VROWW  528              // v-region row: 8 halo + 512 + 8 halo floats
#define VOFF_F 7936             // v-region float offset: 65536B - 16*528*4B = 31744B

typedef float f32x4 __attribute__((ext_vector_type(4)));  // native vec for nt-store

// Fused box filter, DMA-staged, non-temporal output stores:
//   global --(global_load_lds x16B)--> LDS raw[32][512]  (64KB exactly)
//   vertical sliding sum (regs) -> halo-padded v-region (overlaps dead raw rows)
//   horizontal sliding sum (float4) -> global (nt stores: don't evict input
//   from L3 -- input+output = 256MiB exactly fills L3, normal stores thrash it)
// 512 threads (8 waves); LDS 64KB -> 2 blocks/CU.
__device__ __forceinline__ void gload_lds16(const float* g, float* l) {
    __builtin_amdgcn_global_load_lds(
        (const __attribute__((address_space(1))) void*)g,
        (__attribute__((address_space(3))) void*)l, 16, 0, 0);
}

__global__ __launch_bounds__(512, 4)
void box_dma_nt(const float* __restrict__ x, float* __restrict__ out) {
    const int plane = blockIdx.y;              // n*C + c (128 planes)
    const int gy0   = blockIdx.x * ROWS;       // strip start row
    const float* __restrict__ src = x   + (size_t)plane * (W * H);
    float* __restrict__       dst = out + (size_t)plane * (W * H);

    __shared__ __align__(16) float s[INR * W]; // 65,536 B exactly

    const int tid  = threadIdx.x;
    const int wave = tid >> 6;
    const int lane = tid & 63;
    const float inv_k = 1.0f / (float)K;

    // ---- Phase 1: DMA-stage 32 rows x 512 cols. 64 chunks of 1KB; 8/wave.
    #pragma unroll
    for (int i = 0; i < 8; ++i) {
        const int c  = wave * 8 + i;
        const int r  = c >> 1;
        const int hf = c & 1;
        const int gy = gy0 - R + r;
        char* ldsbase = (char*)s + c * 1024;
        if ((unsigned)gy < (unsigned)H) {
            const float* gp = src + gy * W + hf * 256 + lane * 4;
            gload_lds16(gp, (float*)ldsbase);
        } else {
            *reinterpret_cast<float4*>(ldsbase + lane * 16) =
                make_float4(0.f, 0.f, 0.f, 0.f);
        }
    }
    __syncthreads();   // drains vmcnt before barrier

    // ---- Phase 2a: read own column's 32 raw values into regs ----
    const int col = tid;                       // 0..511
    float r32[INR];
    #pragma unroll
    for (int j = 0; j < INR; ++j) r32[j] = s[j * W + col];
    __syncthreads();   // all raw reads complete before v-region overwrites

    // ---- Phase 2b: vertical sliding sums -> halo-padded v rows ----
    {
        float sum = 0.0f;
        #pragma unroll
        for (int j = 0; j < K; ++j) sum += r32[j];
        s[VOFF_F + 0 * VROWW + 8 + col] = sum * inv_k;
        #pragma unroll
        for (int i = 1; i < ROWS; ++i) {
            sum += r32[i + 2 * R] - r32[i - 1];
            s[VOFF_F + i * VROWW + 8 + col] = sum * inv_k;
        }
    }
    // zero the 8-col halos: 16 rows x 4 float4 slots (left 0,4; right 520,524)
    if (tid < 64) {
        const int row = tid >> 2;
        const int q   = tid & 3;
        const int c4  = (q == 0) ? 0 : (q == 1) ? 4 : (q == 2) ? 520 : 524;
        *reinterpret_cast<float4*>(&s[VOFF_F + row * VROWW + c4]) =
            make_float4(0.f, 0.f, 0.f, 0.f);
    }
    __syncthreads();

    // ---- Phase 3: horizontal box sum, float4 LDS reads -> nt float4 stores ----
    // 2048 quads (16 rows x 128) over 512 threads = 4 each
    #pragma unroll
    for (int it = 0; it < 4; ++it) {
        const int q  = tid + it * 512;
        const int y  = q >> 7;                 // 0..15
        const int x4 = (q & 127) * 4;          // 0..508
        const float* vrow = s + VOFF_F + y * VROWW + 8;   // col 0

        const float4 f0 = *reinterpret_cast<const float4*>(vrow + x4 - 8);
        const float4 f1 = *reinterpret_cast<const float4*>(vrow + x4 - 4);
        const float4 f2 = *reinterpret_cast<const float4*>(vrow + x4);
        const float4 f3 = *reinterpret_cast<const float4*>(vrow + x4 + 4);
        const float4 f4 = *reinterpret_cast<const float4*>(vrow + x4 + 8);

        float o0 = f0.x + f0.y + f0.z + f0.w
                 + f1.x + f1.y + f1.z + f1.w
                 + f2.x + f2.y + f2.z + f2.w
                 + f3.x + f3.y + f3.z + f3.w
                 + f4.x;                       // 17 taps: cols x4-8 .. x4+8
        const float o1 = o0 - f0.x + f4.y;
        const float o2 = o1 - f0.y + f4.z;
        const float o3 = o2 - f0.z + f4.w;

        f32x4 o;
        o.x = o0 * inv_k; o.y = o1 * inv_k; o.z = o2 * inv_k; o.w = o3 * inv_k;
        __builtin_nontemporal_store(o,
            reinterpret_cast<f32x4*>(&dst[(gy0 + y) * W + x4]));
    }
}

extern "C" void kernel_launch(void* const* d_in, const int* in_sizes, int n_in,
                              void* d_out, int out_size, void* d_ws, size_t ws_size,
                              hipStream_t stream) {
    const float* x = (const float*)d_in[0];
    float* out = (float*)d_out;
    // x: (8, 16, 512, 512) fp32; r = 8 fixed
    dim3 grid(H / ROWS, 8 * 16);   // (32 strips, 128 planes)
    box_dma_nt<<<grid, dim3(512), 0, stream>>>(x, out);
}

// Round 8
// 60.782 us; speedup vs baseline: 1.0150x; 1.0143x over previous
//
#include <hip/hip_runtime.h>

#define R      8
#define K      17               // 2*r+1
#define W      512
#define H      512
#define ROWS   16               // output rows per block
#define INR    32               // input rows read (ROWS + 2R)
#define LDSW   532              // 8 halo + 512 + 8 halo + 4 pad floats per v row

typedef float f32x4 __attribute__((ext_vector_type(4)));

// Fused box filter v5: register vertical pass (joint-pinned loads for ILP)
//  -> 34KB LDS v-region -> float4 horizontal pass -> nt stores.
// 512 threads (8 waves), LDS 34,048B -> 4 blocks/CU, 32/32 wave slots.
__global__ __launch_bounds__(512, 8)
void box_reg_v5(const float* __restrict__ x, float* __restrict__ out) {
    const int plane = blockIdx.y;              // n*C + c (128 planes)
    const int gy0   = blockIdx.x * ROWS;       // strip start row
    const float* __restrict__ src = x   + (size_t)plane * (W * H);
    float* __restrict__       dst = out + (size_t)plane * (W * H);

    __shared__ __align__(16) float s_v[ROWS][LDSW];   // 34,048 B

    const int tid = threadIdx.x;
    const float inv_k = 1.0f / (float)K;

    // ---- zero the horizontal halo columns (cols -8..-1, 512..519) ----
    if (tid < 64) {
        const int row = tid >> 2;
        const int q   = tid & 3;
        const int c4  = (q == 0) ? 0 : (q == 1) ? 4 : (q == 2) ? 520 : 524;
        *reinterpret_cast<float4*>(&s_v[row][c4]) = make_float4(0.f, 0.f, 0.f, 0.f);
    }

    // ---- Pass 1: vertical box sum. One column per thread, 32 rows ----
    {
        const int col      = tid;              // 0..511 (wave: 256B coalesced)
        const int gy_start = gy0 - R;

        float rr[INR];
        #pragma unroll
        for (int j = 0; j < INR; ++j) {
            const int gy = gy_start + j;
            float v = 0.0f;
            if ((unsigned)gy < (unsigned)H)
                v = src[gy * W + col];
            rr[j] = v;
        }
        // JOINT liveness pins: each asm holds 16 load results live at once,
        // so the compiler must issue the loads as a cluster (R4's per-element
        // pins were interleaved load/pin -> serialized, VGPR=20).
        asm volatile("" : "+v"(rr[0]), "+v"(rr[1]), "+v"(rr[2]), "+v"(rr[3]),
                          "+v"(rr[4]), "+v"(rr[5]), "+v"(rr[6]), "+v"(rr[7]),
                          "+v"(rr[8]), "+v"(rr[9]), "+v"(rr[10]), "+v"(rr[11]),
                          "+v"(rr[12]), "+v"(rr[13]), "+v"(rr[14]), "+v"(rr[15]));
        asm volatile("" : "+v"(rr[16]), "+v"(rr[17]), "+v"(rr[18]), "+v"(rr[19]),
                          "+v"(rr[20]), "+v"(rr[21]), "+v"(rr[22]), "+v"(rr[23]),
                          "+v"(rr[24]), "+v"(rr[25]), "+v"(rr[26]), "+v"(rr[27]),
                          "+v"(rr[28]), "+v"(rr[29]), "+v"(rr[30]), "+v"(rr[31]));

        float s = 0.0f;
        #pragma unroll
        for (int j = 0; j < K; ++j) s += rr[j];
        s_v[0][8 + col] = s * inv_k;
        #pragma unroll
        for (int i = 1; i < ROWS; ++i) {
            s += rr[i + 2 * R] - rr[i - 1];
            s_v[i][8 + col] = s * inv_k;
        }
    }
    __syncthreads();

    // ---- Pass 2: horizontal box sum, float4 LDS reads -> nt float4 stores ----
    // 2048 quads (16 rows x 128) over 512 threads = 4 each
    #pragma unroll
    for (int it = 0; it < 4; ++it) {
        const int q  = tid + it * 512;
        const int y  = q >> 7;                 // 0..15
        const int x4 = (q & 127) * 4;          // 0..508
        const float* vrow = &s_v[y][8];        // col 0

        const float4 f0 = *reinterpret_cast<const float4*>(vrow + x4 - 8);
        const float4 f1 = *reinterpret_cast<const float4*>(vrow + x4 - 4);
        const float4 f2 = *reinterpret_cast<const float4*>(vrow + x4);
        const float4 f3 = *reinterpret_cast<const float4*>(vrow + x4 + 4);
        const float4 f4 = *reinterpret_cast<const float4*>(vrow + x4 + 8);

        float o0 = f0.x + f0.y + f0.z + f0.w
                 + f1.x + f1.y + f1.z + f1.w
                 + f2.x + f2.y + f2.z + f2.w
                 + f3.x + f3.y + f3.z + f3.w
                 + f4.x;                       // 17 taps: cols x4-8 .. x4+8
        const float o1 = o0 - f0.x + f4.y;
        const float o2 = o1 - f0.y + f4.z;
        const float o3 = o2 - f0.z + f4.w;

        f32x4 o;
        o.x = o0 * inv_k; o.y = o1 * inv_k; o.z = o2 * inv_k; o.w = o3 * inv_k;
        __builtin_nontemporal_store(o,
            reinterpret_cast<f32x4*>(&dst[(gy0 + y) * W + x4]));
    }
}

extern "C" void kernel_launch(void* const* d_in, const int* in_sizes, int n_in,
                              void* d_out, int out_size, void* d_ws, size_t ws_size,
                              hipStream_t stream) {
    const float* x = (const float*)d_in[0];
    float* out = (float*)d_out;
    // x: (8, 16, 512, 512) fp32; r = 8 fixed
    dim3 grid(H / ROWS, 8 * 16);   // (32 strips, 128 planes)
    box_reg_v5<<<grid, dim3(512), 0, stream>>>(x, out);
}

// Round 9
// 48.726 us; speedup vs baseline: 1.2662x; 1.2474x over previous
//
#include <hip/hip_runtime.h>

#define R     8
#define K     17               // 2*r+1
#define W     512
#define H     512
#define ROWS  16               // output rows per tile
#define LDSW  532              // 8 halo + 512 + 8 halo + 4 pad floats
#define TILES 8                // strips per block (quarter plane)

typedef float f32x4 __attribute__((ext_vector_type(4)));

// Joint-liveness pin: holds all 16 values live at this point so the 16 loads
// must be issued as a cluster BEFORE this program point (can't be sunk below).
__device__ __forceinline__ void pin16(float* r) {
    asm volatile("" : "+v"(r[0]), "+v"(r[1]), "+v"(r[2]),  "+v"(r[3]),
                      "+v"(r[4]), "+v"(r[5]), "+v"(r[6]),  "+v"(r[7]),
                      "+v"(r[8]), "+v"(r[9]), "+v"(r[10]), "+v"(r[11]),
                      "+v"(r[12]),"+v"(r[13]),"+v"(r[14]), "+v"(r[15]));
}

// Load 16 consecutive rows of one column (zeros outside the image).
__device__ __forceinline__ void load16(const float* __restrict__ src,
                                       int row0, int col, float* d) {
    #pragma unroll
    for (int j = 0; j < 16; ++j) {
        const int gy = row0 + j;
        float v = 0.0f;
        if ((unsigned)gy < (unsigned)H) v = src[gy * W + col];
        d[j] = v;
    }
    pin16(d);
}

// Vertical sliding sums: hi = rows y0-8..y0+7, lo = rows y0+8..y0+23.
__device__ __forceinline__ void vpass(const float* hi, const float* lo,
                                      int col, float (*s_v)[LDSW], float inv_k) {
    float s = 0.0f;
    #pragma unroll
    for (int j = 0; j < 16; ++j) s += hi[j];
    s += lo[0];                                   // 17 rows: y0-8..y0+8
    s_v[0][8 + col] = s * inv_k;
    #pragma unroll
    for (int i = 1; i < 16; ++i) {
        s += lo[i] - hi[i - 1];
        s_v[i][8 + col] = s * inv_k;
    }
}

// Horizontal pass + nt stores (R8's proven quad structure).
__device__ __forceinline__ void hpass_store(const float (*s_v)[LDSW],
                                            float* __restrict__ dst,
                                            int y0, int tid, float inv_k) {
    #pragma unroll
    for (int itq = 0; itq < 4; ++itq) {
        const int q  = tid + itq * 512;
        const int y  = q >> 7;                 // 0..15
        const int x4 = (q & 127) * 4;          // 0..508
        const float* vrow = &s_v[y][8];

        const float4 f0 = *reinterpret_cast<const float4*>(vrow + x4 - 8);
        const float4 f1 = *reinterpret_cast<const float4*>(vrow + x4 - 4);
        const float4 f2 = *reinterpret_cast<const float4*>(vrow + x4);
        const float4 f3 = *reinterpret_cast<const float4*>(vrow + x4 + 4);
        const float4 f4 = *reinterpret_cast<const float4*>(vrow + x4 + 8);

        float o0 = f0.x + f0.y + f0.z + f0.w
                 + f1.x + f1.y + f1.z + f1.w
                 + f2.x + f2.y + f2.z + f2.w
                 + f3.x + f3.y + f3.z + f3.w
                 + f4.x;
        const float o1 = o0 - f0.x + f4.y;
        const float o2 = o1 - f0.y + f4.z;
        const float o3 = o2 - f0.z + f4.w;

        f32x4 o;
        o.x = o0 * inv_k; o.y = o1 * inv_k; o.z = o2 * inv_k; o.w = o3 * inv_k;
        __builtin_nontemporal_store(o,
            reinterpret_cast<f32x4*>(&dst[(y0 + y) * W + x4]));
    }
}

// Pipelined fused box filter: each block marches down 8 strips of one plane.
// Register ping-pong (A/B) rotates the vertical window: 16 new rows/iter,
// issued BEFORE pass2+barriers so HBM runs under the LDS/store phase.
__global__ __launch_bounds__(512, 4)
void box_pipe(const float* __restrict__ x, float* __restrict__ out) {
    const int bid   = blockIdx.x;              // 0..511
    const int plane = bid >> 2;                // 128 planes
    const int s0    = (bid & 3) * TILES;       // first strip: 0/8/16/24
    const float* __restrict__ src = x   + (size_t)plane * (W * H);
    float* __restrict__       dst = out + (size_t)plane * (W * H);

    __shared__ __align__(16) float s_v[ROWS][LDSW];   // 34,048 B

    const int tid = threadIdx.x;
    const int col = tid;                       // 0..511
    const float inv_k = 1.0f / (float)K;

    // zero halo cols once (visible to pass2 via the in-loop barrier)
    if (tid < 64) {
        const int row = tid >> 2;
        const int q   = tid & 3;
        const int c4  = (q == 0) ? 0 : (q == 1) ? 4 : (q == 2) ? 520 : 524;
        *reinterpret_cast<float4*>(&s_v[row][c4]) = make_float4(0.f, 0.f, 0.f, 0.f);
    }

    float A[16], B[16];
    const int ybase = s0 * ROWS;

    // prologue: A = rows ybase-8..ybase+7 (hi), B = rows ybase+8..ybase+23 (lo)
    load16(src, ybase - R, col, A);
    load16(src, ybase + R, col, B);

    for (int it = 0; it < TILES / 2; ++it) {
        // ---- even tile: hi=A, lo=B; next rows -> A ----
        {
            const int y0 = (s0 + 2 * it) * ROWS;
            vpass(A, B, col, s_v, inv_k);
            load16(src, y0 + 24, col, A);      // next tile's lo, in flight below
            __syncthreads();
            hpass_store(s_v, dst, y0, tid, inv_k);
            __syncthreads();
        }
        // ---- odd tile: hi=B, lo=A; next rows -> B ----
        {
            const int y0 = (s0 + 2 * it + 1) * ROWS;
            vpass(B, A, col, s_v, inv_k);
            if (it < TILES / 2 - 1)
                load16(src, y0 + 24, col, B);
            __syncthreads();
            hpass_store(s_v, dst, y0, tid, inv_k);
            __syncthreads();
        }
    }
}

extern "C" void kernel_launch(void* const* d_in, const int* in_sizes, int n_in,
                              void* d_out, int out_size, void* d_ws, size_t ws_size,
                              hipStream_t stream) {
    const float* x = (const float*)d_in[0];
    float* out = (float*)d_out;
    // x: (8, 16, 512, 512) fp32; r = 8 fixed
    box_pipe<<<dim3(512), dim3(512), 0, stream>>>(x, out);
}